// Round 5
// baseline (450.539 us; speedup 1.0000x reference)
//
#include <hip/hip_runtime.h>
#include <hip/hip_bf16.h>

typedef short bf16x8 __attribute__((ext_vector_type(8)));
typedef float f32x4 __attribute__((ext_vector_type(4)));

constexpr int C_IN = 64, H_IN = 128, W_IN = 128, C_OUT = 128, OH = 126, OW = 126;
constexpr int PAD = 72;       // legacy-path LDS stride
constexpr float SUBC = 0.7f;  // SUB1 + SUB2

constexpr size_t WR_BYTES = (size_t)9 * C_OUT * C_IN * 2;           // 147456
constexpr size_t XB_BYTES = (size_t)32 * H_IN * W_IN * C_IN * 2;    // 64 MiB

__device__ __forceinline__ void gl_lds16(const void* g, void* l) {
    __builtin_amdgcn_global_load_lds(
        (const __attribute__((address_space(1))) unsigned int*)g,
        (__attribute__((address_space(3))) unsigned int*)l, 16, 0, 0);
}

// Weights OIHW fp32 -> Wr[kh][kw][co][granule-swizzled ci] bf16.
// Content swizzle: chunk cb of row co stored at granule (cb ^ (co&7)) -> linear
// global_load_lds staging + XOR'd b128 reads are bank-balanced (8 lanes/class).
__global__ void reorder_weights(const float* __restrict__ w, __hip_bfloat16* __restrict__ wr) {
    int o = blockIdx.x * 256 + threadIdx.x;
    if (o >= 9 * C_OUT * C_IN) return;
    int ci = o & 63;
    int co = (o >> 6) & 127;
    int k9 = o >> 13;             // kh*3+kw
    int kh = k9 / 3, kw = k9 % 3;
    int cb = ci >> 3, e = ci & 7;
    int dst = (k9 << 13) + (co << 6) + (((cb ^ co) & 7) << 3) + e;
    wr[dst] = __float2bfloat16(w[((co * C_IN + ci) * 3 + kh) * 3 + kw]);
}

// Prepass: x NCHW fp32 -> xb[n][h][w][granule-swizzled ci] bf16 (one-time transpose+cvt,
// streaming/latency-hidden; removes all cvt VALU from conv_mish's barrier-bounded staging)
__global__ __launch_bounds__(256) void convert_x(const float* __restrict__ x, __hip_bfloat16* __restrict__ xb) {
    int b   = blockIdx.x;            // (n,h) : 32*128 = 4096
    int tid = threadIdx.x;
    const float* src = x + (size_t)(b >> 7) * (C_IN * H_IN * W_IN) + (size_t)(b & 127) * W_IN;
    __hip_bfloat16* dst = xb + (size_t)b * (W_IN * C_IN);
    for (int r = 0; r < 4; ++r) {
        int t  = tid + r * 256;      // (w, ci-block)
        int cb = t & 7;
        int w  = t >> 3;
        alignas(16) __hip_bfloat16 tmp[8];
        #pragma unroll
        for (int e = 0; e < 8; ++e)
            tmp[e] = __float2bfloat16(src[(size_t)(cb * 8 + e) * (H_IN * W_IN) + w]);
        *(bf16x8*)&dst[(w << 6) + (((cb ^ w) & 7) << 3)] = *(const bf16x8*)tmp;  // coalesced: permutes within 128B
    }
}

// m97-style pipelined implicit GEMM: one block per (n,oh); 9 steps (kh,kw);
// Xs[2]+Bs[2] double-buffer; global_load_lds prefetch issued BEFORE compute so the
// compiler's vmcnt(0) drain at the barrier finds loads already landed. 10 barriers vs 21.
__global__ __launch_bounds__(256, 2) void conv_mish_pipe(
    const __hip_bfloat16* __restrict__ xb, const __hip_bfloat16* __restrict__ wr,
    const float* __restrict__ bias, float* __restrict__ out)
{
    __shared__ alignas(16) __hip_bfloat16 smem[4 * 8192];  // [Xs0][Xs1][Bs0][Bs1], 64 KB

    // XCD-aware swizzle: each XCD (b%8) gets a contiguous run of (n,oh)
    int b  = blockIdx.x;
    int lb = (b & 7) * 504 + (b >> 3);   // 4032 = 8 * 504
    int n  = lb / OH;
    int oh = lb % OH;

    int tid  = threadIdx.x;
    int lane = tid & 63;
    int wv   = tid >> 6;
    int wm   = wv >> 1;
    int wn   = wv & 1;
    int quad = lane >> 4;
    int l16  = lane & 15;

    f32x4 acc[4][4] = {};

    const __hip_bfloat16* xbase = xb + ((size_t)n * H_IN + oh) * (W_IN * C_IN);

    // copy 16KB linearly: wave wv owns bytes [wv*4K, wv*4K+4K); dest base wave-uniform
    auto stage = [&](const __hip_bfloat16* src, __hip_bfloat16* dst) {
        const char* s = (const char*)src + (wv << 12) + (lane << 4);
        char* d = (char*)dst + (wv << 12);
        #pragma unroll
        for (int r = 0; r < 4; ++r)
            gl_lds16(s + r * 1024, d + r * 1024);
    };

    // prologue: Xs buf0 <- input row oh ; Bs buf0 <- weight slice 0
    stage(xbase, smem);
    stage(wr, smem + 2 * 8192);
    __syncthreads();   // vmcnt drained here -> buffers valid

    for (int s = 0; s < 9; ++s) {
        int kh = s / 3, kw = s - kh * 3;
        int p = s & 1, q = kh & 1;
        // prefetch next step into the opposite buffers (their readers finished before last barrier)
        if (s < 8) stage(wr + (size_t)(s + 1) * 8192, smem + (2 + (p ^ 1)) * 8192);
        if (kw == 0 && kh < 2) stage(xbase + (size_t)(kh + 1) * (W_IN * C_IN), smem + (q ^ 1) * 8192);

        const __hip_bfloat16* Xp = smem + q * 8192;
        const __hip_bfloat16* Bp = smem + (2 + p) * 8192;
        #pragma unroll
        for (int half = 0; half < 2; ++half) {
            int g = half * 4 + quad;     // ci granule index 0..7
            bf16x8 a[4], bfr[4];
            #pragma unroll
            for (int j = 0; j < 4; ++j) {
                int co = wn * 64 + j * 16 + l16;
                bfr[j] = *(const bf16x8*)&Bp[(co << 6) + (((g ^ co) & 7) << 3)];
            }
            #pragma unroll
            for (int i = 0; i < 4; ++i) {
                int m = wm * 64 + i * 16 + l16 + kw;
                int widx = m > 127 ? 127 : m;    // pad rows read garbage, never stored
                a[i] = *(const bf16x8*)&Xp[(widx << 6) + (((g ^ widx) & 7) << 3)];
            }
            #pragma unroll
            for (int i = 0; i < 4; ++i)
                #pragma unroll
                for (int j = 0; j < 4; ++j)
                    acc[i][j] = __builtin_amdgcn_mfma_f32_16x16x32_bf16(a[i], bfr[j], acc[i][j], 0, 0, 0);
        }
        if (s < 8) __syncthreads();  // drains this step's prefetch (issued ~600cy ago) + guards buffer swap
    }

    // ---- epilogue: bias - 0.7, Mish = v * t/(t+2), t = e*(e+2), e = exp(v) ----
    for (int j = 0; j < 4; ++j) {
        int co = wn * 64 + j * 16 + l16;
        float bb = bias[co] - SUBC;
        for (int i = 0; i < 4; ++i) {
            int ow0 = wm * 64 + i * 16 + quad * 4;
            float o[4];
            for (int r = 0; r < 4; ++r) {
                float v = acc[i][j][r] + bb;
                float e = __expf(v);
                float t = e * (e + 2.0f);
                float m = v * t * __builtin_amdgcn_rcpf(t + 2.0f);
                o[r] = (v > 20.0f) ? v : m;
            }
            float* dst = out + (((size_t)n * C_OUT + co) * OH + oh) * OW + ow0;
            float2 p0; p0.x = o[0]; p0.y = o[1];
            *(float2*)dst = p0;
            if (ow0 + 2 < OW) {
                float2 p1; p1.x = o[2]; p1.y = o[3];
                *(float2*)(dst + 2) = p1;
            }
        }
    }
}

// Fallback (ws too small for xb): R3-proven kernel, adapted to the swizzled Wr content
// (Bs staged linearly -> read applies the same granule XOR).
__global__ __launch_bounds__(256, 2) void conv_mish_legacy(
    const float* __restrict__ x, const __hip_bfloat16* __restrict__ wr,
    const float* __restrict__ bias, float* __restrict__ out)
{
    __shared__ __hip_bfloat16 Xs[128 * PAD];
    __shared__ __hip_bfloat16 Bs[128 * PAD];

    int b = blockIdx.x;
    int lb = (b & 7) * 504 + (b >> 3);
    int n  = lb / OH;
    int oh = lb % OH;

    int tid  = threadIdx.x;
    int lane = tid & 63;
    int wv   = tid >> 6;
    int wm   = wv >> 1;
    int wn   = wv & 1;
    int quad = lane >> 4;
    int l16  = lane & 15;

    f32x4 acc[4][4] = {};
    const float* xn = x + (size_t)n * C_IN * H_IN * W_IN;

    for (int kh = 0; kh < 3; ++kh) {
        __syncthreads();
        {
            int h = oh + kh;
            for (int r = 0; r < 4; ++r) {
                int t  = tid + r * 256;
                int w  = t & 127;
                int cb = t >> 7;
                const float* gp = xn + ((size_t)(cb * 8) * H_IN + h) * W_IN + w;
                alignas(16) __hip_bfloat16 tmp[8];
                #pragma unroll
                for (int e = 0; e < 8; ++e)
                    tmp[e] = __float2bfloat16(gp[(size_t)e * (H_IN * W_IN)]);
                *(bf16x8*)&Xs[w * PAD + cb * 8] = *(const bf16x8*)tmp;
            }
        }
        {
            const __hip_bfloat16* src = wr + ((kh * 3 + 0) << 13);
            for (int r = 0; r < 4; ++r) {
                int c   = tid + r * 256;
                int co  = c >> 3;
                int ci8 = (c & 7) << 3;
                *(bf16x8*)&Bs[co * PAD + ci8] = *(const bf16x8*)(src + co * 64 + ci8);
            }
        }
        __syncthreads();

        for (int kw = 0; kw < 3; ++kw) {
            if (kw) {
                __syncthreads();
                const __hip_bfloat16* src = wr + ((kh * 3 + kw) << 13);
                for (int r = 0; r < 4; ++r) {
                    int c   = tid + r * 256;
                    int co  = c >> 3;
                    int ci8 = (c & 7) << 3;
                    *(bf16x8*)&Bs[co * PAD + ci8] = *(const bf16x8*)(src + co * 64 + ci8);
                }
                __syncthreads();
            }
            #pragma unroll
            for (int half = 0; half < 2; ++half) {
                int k0 = half * 32 + quad * 8;
                int g  = half * 4 + quad;
                bf16x8 a[4], bfr[4];
                #pragma unroll
                for (int j = 0; j < 4; ++j) {
                    int co = wn * 64 + j * 16 + l16;
                    bfr[j] = *(const bf16x8*)&Bs[co * PAD + (((g ^ co) & 7) << 3)];  // swizzled Wr content
                }
                #pragma unroll
                for (int i = 0; i < 4; ++i) {
                    int m = wm * 64 + i * 16 + l16;
                    int widx = m + kw; if (widx > 127) widx = 127;
                    a[i] = *(const bf16x8*)&Xs[widx * PAD + k0];
                }
                #pragma unroll
                for (int i = 0; i < 4; ++i)
                    #pragma unroll
                    for (int j = 0; j < 4; ++j)
                        acc[i][j] = __builtin_amdgcn_mfma_f32_16x16x32_bf16(a[i], bfr[j], acc[i][j], 0, 0, 0);
            }
        }
    }

    for (int j = 0; j < 4; ++j) {
        int co = wn * 64 + j * 16 + l16;
        float bb = bias[co] - SUBC;
        for (int i = 0; i < 4; ++i) {
            int ow0 = wm * 64 + i * 16 + quad * 4;
            float o[4];
            for (int r = 0; r < 4; ++r) {
                float v = acc[i][j][r] + bb;
                float e = __expf(v);
                float t = e * (e + 2.0f);
                float m = v * t * __builtin_amdgcn_rcpf(t + 2.0f);
                o[r] = (v > 20.0f) ? v : m;
            }
            float* dst = out + (((size_t)n * C_OUT + co) * OH + oh) * OW + ow0;
            float2 p0; p0.x = o[0]; p0.y = o[1];
            *(float2*)dst = p0;
            if (ow0 + 2 < OW) {
                float2 p1; p1.x = o[2]; p1.y = o[3];
                *(float2*)(dst + 2) = p1;
            }
        }
    }
}

extern "C" void kernel_launch(void* const* d_in, const int* in_sizes, int n_in,
                              void* d_out, int out_size, void* d_ws, size_t ws_size,
                              hipStream_t stream) {
    const float* x    = (const float*)d_in[0];
    const float* w    = (const float*)d_in[1];
    const float* bias = (const float*)d_in[2];
    float* out        = (float*)d_out;
    __hip_bfloat16* wr = (__hip_bfloat16*)d_ws;

    reorder_weights<<<(9 * C_OUT * C_IN + 255) / 256, 256, 0, stream>>>(w, wr);

    if (ws_size >= WR_BYTES + XB_BYTES) {
        __hip_bfloat16* xb = (__hip_bfloat16*)((char*)d_ws + WR_BYTES);
        convert_x<<<32 * H_IN, 256, 0, stream>>>(x, xb);
        conv_mish_pipe<<<32 * OH, 256, 0, stream>>>(xb, wr, bias, out);
    } else {
        conv_mish_legacy<<<32 * OH, 256, 0, stream>>>(x, wr, bias, out);
    }
}